// Round 7
// baseline (178.050 us; speedup 1.0000x reference)
//
#include <hip/hip_runtime.h>
#include <cstdint>

#define NROW 6144
#define KDIM 128
#define NLAB 200
#define C_COEF (-0.28719499063341177f)   /* -ln(99)/16 ; A_COEF = 2 exactly */
#define UBV 64.0f

typedef _Float16 f16x8 __attribute__((ext_vector_type(8)));
typedef _Float16 f16x2 __attribute__((ext_vector_type(2)));
typedef float f32x4 __attribute__((ext_vector_type(4)));
typedef __attribute__((address_space(1))) const void as1c_void;
typedef __attribute__((address_space(3))) void as3_void;

union U8 { f16x8 h; unsigned u[4]; f16x2 p[4]; };
union CV16 { _Float16 h; unsigned short us; };

__device__ __forceinline__ float softplus_f(float x){
  return fmaxf(x, 0.f) + __logf(1.f + __expf(-fabsf(x)));
}
__device__ __forceinline__ float waveRedF(float v){
#pragma unroll
  for (int o = 32; o; o >>= 1) v += __shfl_down(v, o, 64);
  return v;
}
__device__ __forceinline__ float bfRedF(float v){
#pragma unroll
  for (int o = 32; o; o >>= 1) v += __shfl_xor(v, o, 64);
  return v;
}
__device__ __forceinline__ int bfMaxI(int v){
#pragma unroll
  for (int o = 32; o; o >>= 1){ int x = __shfl_xor(v, o, 64); v = v > x ? v : x; }
  return v;
}
// sortable key: ascending key == ascending value (f16, no NaN present)
__device__ __forceinline__ float val_of_key(unsigned key){
  unsigned bits = (key & 0x8000u) ? (key ^ 0x8000u) : (key ^ 0xFFFFu);
  CV16 cv; cv.us = (unsigned short)bits;
  return (float)cv.h;
}

// ---------------- fused: labels/member-lists (4 rows/block) | tanh + q-loss ----
__global__ __launch_bounds__(256) void k_labtanh(const int* __restrict__ y,
    unsigned char* __restrict__ lab, int* __restrict__ cnt, int* __restrict__ simIdx,
    const float* __restrict__ u, _Float16* __restrict__ uhswz, float* __restrict__ accf){
  const int bid = blockIdx.x;
  const int tid = threadIdx.x;
  const int NLB = NROW / 4;                        // 1536 label blocks
  if (bid < NLB){                                  // ---- label part: wave per row ----
    const int lane = tid & 63;
    const int row = bid * 4 + (tid >> 6);
    if (lane < NLAB / 4){
      const int4 v = ((const int4*)(y + (size_t)row * NLAB))[lane];
      int t = -1;
      if (v.x != 0) t = 4 * lane;
      if (v.y != 0) t = 4 * lane + 1;
      if (v.z != 0) t = 4 * lane + 2;
      if (v.w != 0) t = 4 * lane + 3;
      if (t >= 0){
        lab[row] = (unsigned char)t;
        int p = atomicAdd(&cnt[t], 1);
        if (p < 512) simIdx[t * 512 + p] = row;
      }
    }
    return;
  }
  // ---- tanh part ----
  const int gid = (bid - NLB) * 256 + tid;
  const int row = gid >> 4;
  const int h = gid & 15;
  const int g = h ^ (row & 7);
  const float* sp = u + (size_t)row * KDIM + g * 8;
  float q = 0.f;
  f16x8 o;
#pragma unroll
  for (int t = 0; t < 8; t++){
    float x = sp[t];
    float e2 = __expf(2.f * x);
    float th = 1.f - 2.f * __builtin_amdgcn_rcpf(e2 + 1.f);  // tanh, ~1e-6 err
    float sg = (th > 0.f) ? 1.f : ((th < 0.f) ? -1.f : 0.f);
    float d = th - sg;
    q += d * d;
    o[t] = (_Float16)th;
  }
  *(f16x8*)(uhswz + (size_t)row * KDIM + h * 8) = o;
  q = waveRedF(q);
  __shared__ float qb[4];
  if ((tid & 63) == 0) qb[tid >> 6] = q;
  __syncthreads();
  if (tid == 0) atomicAdd(&accf[0], qb[0] + qb[1] + qb[2] + qb[3]);
}

// ---------------- inner = uh @ uh^T -> f16 out via LDS-transpose epilogue ----------------
__global__ __launch_bounds__(256) void k_mm(const _Float16* __restrict__ A,
    _Float16* __restrict__ out, int row0){
  __shared__ __align__(16) _Float16 SH[2 * 128 * KDIM];   // 64 KB: As|Bs, reused as Cs
  _Float16* As = SH;
  _Float16* Bs = SH + 128 * KDIM;
  const int tid = threadIdx.x;
  const int wav = tid >> 6, lane = tid & 63;
  const int bj = blockIdx.x, bi = blockIdx.y;

  const char* Ag = (const char*)(A + (size_t)(row0 + bi * 128) * KDIM);
  const char* Bg = (const char*)(A + (size_t)(bj * 128) * KDIM);
  char* Asb = (char*)As;
  char* Bsb = (char*)Bs;
#pragma unroll
  for (int t = 0; t < 8; t++){
    const int ub = wav * 8192 + t * 1024;
    __builtin_amdgcn_global_load_lds((as1c_void*)(Ag + ub + lane * 16),
                                     (as3_void*)(Asb + ub), 16, 0, 0);
    __builtin_amdgcn_global_load_lds((as1c_void*)(Bg + ub + lane * 16),
                                     (as3_void*)(Bsb + ub), 16, 0, 0);
  }
  __syncthreads();

  const int quad = lane >> 4, l16 = lane & 15;
  const int wm = (wav >> 1) * 64, wn = (wav & 1) * 64;
  f32x4 acc[4][4];
#pragma unroll
  for (int im = 0; im < 4; im++)
#pragma unroll
    for (int in = 0; in < 4; in++)
      acc[im][in] = (f32x4){0.f, 0.f, 0.f, 0.f};

#pragma unroll
  for (int kb = 0; kb < 4; kb++){
    f16x8 af[4], bf[4];
#pragma unroll
    for (int i = 0; i < 4; i++){
      const int m = wm + i * 16 + l16;
      const int gidx = kb * 4 + quad;
      af[i] = *(const f16x8*)(Asb + m * 256 + ((gidx ^ (m & 7)) << 4));
      const int n = wn + i * 16 + l16;
      bf[i] = *(const f16x8*)(Bsb + n * 256 + ((gidx ^ (n & 7)) << 4));
    }
#pragma unroll
    for (int im = 0; im < 4; im++)
#pragma unroll
      for (int in = 0; in < 4; in++)
        acc[im][in] = __builtin_amdgcn_mfma_f32_16x16x32_f16(af[im], bf[in], acc[im][in], 0, 0, 0);
  }
  __syncthreads();                                 // done reading As/Bs

  _Float16* Cs = SH;                               // 128*132*2 = 33792 B
#pragma unroll
  for (int im = 0; im < 4; im++)
#pragma unroll
    for (int in = 0; in < 4; in++)
#pragma unroll
      for (int r = 0; r < 4; r++){
        const int rl = wm + im * 16 + quad * 4 + r;
        const int cl = wn + in * 16 + l16;
        Cs[rl * 132 + cl] = (_Float16)acc[im][in][r];
      }
  __syncthreads();

  _Float16* obase = out + (size_t)(bi * 128) * NROW + (size_t)bj * 128;
  const int s = tid & 15;
#pragma unroll
  for (int i = 0; i < 8; i++){
    const int r = (tid >> 4) + i * 16;
    f16x8 vv = *(const f16x8*)(Cs + r * 132 + s * 8);
    *(f16x8*)(obase + (size_t)r * NROW + s * 8) = vv;
  }
}

// ---------------- per-row stats + loss: BLOCK PER ROW (256 thr), LDS-staged row ----
// Row loaded from HBM once into LDS (12 KB); radix + loss sweeps read LDS.
// Wave-private L1 histogram copies; shared L2 histogram (rare atomics).
// 24 element-visits per thread per sweep -> 4x the MLP of wave-per-row.
// LDS ~19.6 KB -> 8 blocks/CU (32 waves, full occupancy).
__global__ __launch_bounds__(256) void k_stats(const _Float16* __restrict__ buf,
    const unsigned char* __restrict__ lab, const int* __restrict__ cnt,
    const int* __restrict__ simIdx, float* __restrict__ rowRes, int row0){
  __shared__ __align__(16) _Float16 rowh[NROW];   // 12288 B
  __shared__ int   hist[4][257];                  // 4112 B (per-wave L1 copies)
  __shared__ int   hist2[257];                    // 1028 B (shared L2)
  __shared__ float simv[512];                     // 2048 B
  __shared__ float rbuf[32];                      // 128 B
  __shared__ float ctlF[2];
  __shared__ int   ctlI[2];
  const int tid = threadIdx.x;
  const int lane = tid & 63;
  const int wav = tid >> 6;
  const int lrow = blockIdx.x;                    // chunk-local row
  const int row = row0 + lrow;
  const int myl = lab[row];
  const int n_sim = cnt[myl];
  const int n_dis = NROW - n_sim;
  if (n_dis == 0 || n_sim == 0) return;           // block-uniform exit
  const int k1 = n_dis - (n_dis * 9) / 10;        // tail count (top-10% dissimilar)
  const int k2 = n_sim - (n_sim * 9) / 10;        // head count (bottom-10% similar)
  const int ns = (n_sim < 512) ? n_sim : 512;

  int* myh = hist[wav];
#pragma unroll
  for (int r = 0; r < 4; r++) myh[lane + 64 * r] = 0;
  if (lane == 0) myh[256] = 0;
  if (tid < 256) hist2[tid] = 0;
  if (tid == 0) hist2[256] = 0;
  __syncthreads();                                // B0

  // ---- P0: load row -> LDS, L1 histogram, total sum ----
  const f16x8* src = (const f16x8*)(buf + (size_t)lrow * NROW);
  float sumAll = 0.f;
  const f16x2 ones = (f16x2){(_Float16)1.f, (_Float16)1.f};
#pragma unroll
  for (int it = 0; it < 3; ++it){
    const int g8 = it * 256 + tid;
    U8 x; x.h = src[g8];
    ((f16x8*)rowh)[g8] = x.h;
#pragma unroll
    for (int k = 0; k < 4; k++){
      unsigned wv = x.u[k];
      unsigned m = (wv >> 15) & 0x00010001u;
      unsigned key2 = wv ^ 0x80008000u ^ (m * 0x7FFFu);   // two sortable u16 keys
      atomicAdd(&myh[(key2 >> 8) & 0xFFu], 1);
      atomicAdd(&myh[key2 >> 24], 1);
#if __has_builtin(__builtin_amdgcn_fdot2)
      sumAll = __builtin_amdgcn_fdot2(x.p[k], ones, sumAll, false);
#else
      sumAll += (float)x.h[2 * k] + (float)x.h[2 * k + 1];
#endif
    }
  }
  sumAll = waveRedF(sumAll);
  if (lane == 0) rbuf[wav] = sumAll;
  __syncthreads();                                // B1: rowh + L1 adds + rbuf[0..3]

  // ---- gather sim values; subtract from L1 histogram ----
  float sumS = 0.f;
  for (int t = tid; t < ns; t += 256){
    int idx = simIdx[myl * 512 + t];
    CV16 cv; cv.h = rowh[idx];
    unsigned bits = (unsigned)cv.us;
    unsigned key = bits ^ 0x8000u ^ ((bits >> 15) * 0x7FFFu);
    float v = (float)cv.h;
    simv[t] = v; sumS += v;
    atomicAdd(&myh[key >> 8], -1);
  }
  sumS = waveRedF(sumS);
  if (lane == 0) rbuf[4 + wav] = sumS;
  __syncthreads();                                // B2: L1 final, simv, rbuf[4..7]

  const float sumAllT = rbuf[0] + rbuf[1] + rbuf[2] + rbuf[3];
  const float sumST   = rbuf[4] + rbuf[5] + rbuf[6] + rbuf[7];
  const float sumD = sumAllT - sumST;

  // ---- L1 select (per-wave redundant): pivot high-byte bucket ----
  int cArr[4];
  {
    int4 a = *(const int4*)&hist[0][4 * lane];
    int4 b = *(const int4*)&hist[1][4 * lane];
    int4 c = *(const int4*)&hist[2][4 * lane];
    int4 d = *(const int4*)&hist[3][4 * lane];
    cArr[0] = a.x + b.x + c.x + d.x;
    cArr[1] = a.y + b.y + c.y + d.y;
    cArr[2] = a.z + b.z + c.z + d.z;
    cArr[3] = a.w + b.w + c.w + d.w;
  }
  int part = cArr[0] + cArr[1] + cArr[2] + cArr[3];
  int suf = part;
#pragma unroll
  for (int o = 1; o < 64; o <<= 1){
    int x = __shfl_down(suf, o, 64);
    if (lane + o < 64) suf += x;
  }
  int cum = suf - part;
  int encB = -1, krF = 0;
#pragma unroll
  for (int d = 3; d >= 0; --d){
    int cd = cArr[d];
    if (k1 > cum && k1 <= cum + cd){ encB = 4 * lane + d; krF = k1 - cum; }
    cum += cd;
  }
  const int hbStar = bfMaxI(encB);
  const int kr1 = bfMaxI(krF);

  // ---- pass B (LDS): above-bucket sum + L2 histogram ----
  float sAb = 0.f;
#pragma unroll
  for (int it = 0; it < 3; ++it){
    U8 x; x.h = ((const f16x8*)rowh)[it * 256 + tid];
#pragma unroll
    for (int k = 0; k < 4; k++){
      unsigned wv = x.u[k];
      unsigned m = (wv >> 15) & 0x00010001u;
      unsigned key2 = wv ^ 0x80008000u ^ (m * 0x7FFFu);
      int hbLo = (key2 >> 8) & 0xFF;
      int hbHi = key2 >> 24;
      if (hbLo > hbStar) sAb += (float)x.h[2 * k];
      else if (hbLo == hbStar) atomicAdd(&hist2[key2 & 0xFFu], 1);
      if (hbHi > hbStar) sAb += (float)x.h[2 * k + 1];
      else if (hbHi == hbStar) atomicAdd(&hist2[(key2 >> 16) & 0xFFu], 1);
    }
  }
  for (int t = tid; t < ns; t += 256){
    float v = simv[t];
    CV16 cv; cv.h = (_Float16)v;                  // exact roundtrip
    unsigned bits = (unsigned)cv.us;
    unsigned key = bits ^ 0x8000u ^ ((bits >> 15) * 0x7FFFu);
    int hb = (int)(key >> 8);
    if (hb > hbStar) sAb -= v;
    else if (hb == hbStar) atomicAdd(&hist2[key & 0xFFu], -1);
  }
  sAb = waveRedF(sAb);
  if (lane == 0) rbuf[8 + wav] = sAb;
  __syncthreads();                                // B3: hist2 final, rbuf[8..11]
  const float sAbT = rbuf[8] + rbuf[9] + rbuf[10] + rbuf[11];

  // ---- L2 select (per-wave redundant): exact pivot + above-pivot sum ----
  int c2[4];
  { int4 c4 = *(const int4*)&hist2[4 * lane];
    c2[0] = c4.x; c2[1] = c4.y; c2[2] = c4.z; c2[3] = c4.w; }
  part = c2[0] + c2[1] + c2[2] + c2[3];
  suf = part;
#pragma unroll
  for (int o = 1; o < 64; o <<= 1){
    int x = __shfl_down(suf, o, 64);
    if (lane + o < 64) suf += x;
  }
  cum = suf - part;
  int encL = -1, g2F = 0;
#pragma unroll
  for (int d = 3; d >= 0; --d){
    int cd = c2[d];
    if (kr1 > cum && kr1 <= cum + cd){ encL = 4 * lane + d; g2F = cum; }
    cum += cd;
  }
  const int lbStar = bfMaxI(encL);
  const int gt2 = bfMaxI(g2F);
  float sumIn = 0.f;
#pragma unroll
  for (int d = 0; d < 4; d++){
    int lb = 4 * lane + d;
    if (lb > lbStar) sumIn += (float)c2[d] * val_of_key((unsigned)((hbStar << 8) | lb));
  }
  sumIn = bfRedF(sumIn);
  const float piv = val_of_key((unsigned)((hbStar << 8) | lbStar));
  const float dSum = sAbT + sumIn + (float)(kr1 - gt2) * piv;

  // ---- sMin: k2-th smallest similar (rank-count over 256 threads) ----
  for (int t = tid; t < ns; t += 256){
    float vt = simv[t];
    int lt = 0, eq = 0;
    for (int j = 0; j < ns; j++){
      float vj = simv[j];                         // broadcast read
      lt += (vj < vt); eq += (vj == vt);
    }
    if (lt < k2 && k2 <= lt + eq){ ctlF[0] = vt; ctlI[0] = lt; }  // benign race (ties -> same pair)
  }
  __syncthreads();                                // B4: ctl ready
  const float piv2 = ctlF[0];
  const int ltS = ctlI[0];
  float slt = 0.f;
  for (int t = tid; t < ns; t += 256){
    float v = simv[t];
    if (v < piv2) slt += v;
  }
  slt = waveRedF(slt);
  if (lane == 0) rbuf[12 + wav] = slt;
  __syncthreads();                                // B5: rbuf[12..15]
  const float sltT = rbuf[12] + rbuf[13] + rbuf[14] + rbuf[15];
  const float sSum = sltT + (float)(k2 - ltS) * piv2;

  // ---- BP / BPd (all threads redundant) ----
  const float meanS  = fminf(fmaxf(sumST / fmaxf((float)n_sim, 1.f), 0.f), UBV);
  const float meanDS = fminf(fmaxf(sumD / fmaxf((float)n_dis, 1.f), 0.f), UBV);
  const float dMax   = fminf(fmaxf(dSum / fmaxf((float)k1, 1.f), 0.f), UBV);
  const float sMin   = fminf(fmaxf(sSum / fmaxf((float)k2, 1.f), 0.f), UBV);
  const float BP  = meanS - (UBV - meanS) / UBV * fabsf(meanS - dMax);
  const float BPd = meanDS + meanDS / UBV * fabsf(meanDS - sMin);

  // ---- loss: maskless sweep over LDS row + sim corrections ----
  float an = 0.f; int ties = 0;
#pragma unroll
  for (int it = 0; it < 3; ++it){
    f16x8 h8 = ((const f16x8*)rowh)[it * 256 + tid];
#pragma unroll
    for (int e = 0; e < 8; e++){
      float v = (float)h8[e];
      float dcd = v - BPd;
      float f = ((dcd < 0.f) ? C_COEF : 2.f * C_COEF) * dcd;
      an += softplus_f(-f);
      ties += (dcd == 0.f);
    }
  }
  float spSim = 0.f; int tiesSim = 0;
  float ap = 0.f, cp = 0.f;
  for (int t = tid; t < ns; t += 256){
    float v = simv[t];
    float dcd = v - BPd;
    if (dcd == 0.f) tiesSim++;
    else {
      float f = ((dcd < 0.f) ? C_COEF : 2.f * C_COEF) * dcd;
      spSim += softplus_f(-f);
    }
    if (v != BP){
      float dc = v - BP;
      float f = (v > BP) ? C_COEF * dc : (2.f * C_COEF) * dc;
      ap += softplus_f(f); cp += 1.f;
    }
  }
  an = waveRedF(an); ap = waveRedF(ap); cp = waveRedF(cp);
  spSim = waveRedF(spSim);
  float tiesF = waveRedF((float)ties);
  float tiesSimF = waveRedF((float)tiesSim);
  if (lane == 0){
    rbuf[wav] = an; rbuf[4 + wav] = ap; rbuf[8 + wav] = cp;
    rbuf[16 + wav] = spSim; rbuf[20 + wav] = tiesF; rbuf[24 + wav] = tiesSimF;
  }
  __syncthreads();                                // B6
  if (tid == 0){
    float anT = rbuf[0] + rbuf[1] + rbuf[2] + rbuf[3];
    float apT = rbuf[4] + rbuf[5] + rbuf[6] + rbuf[7];
    float cpT = rbuf[8] + rbuf[9] + rbuf[10] + rbuf[11];
    float spT = rbuf[16] + rbuf[17] + rbuf[18] + rbuf[19];
    float tiesT = rbuf[20] + rbuf[21] + rbuf[22] + rbuf[23];
    float tiesSimT = rbuf[24] + rbuf[25] + rbuf[26] + rbuf[27];
    const float L = __logf(1.f + __expf(-0.f));   // value added per tie in sweep
    float anF = anT - tiesT * L - spT;
    float cnF = (float)n_dis - (tiesT - tiesSimT);
    float4 r;
    r.x = apT / fmaxf(cpT, 1.f);
    r.y = anF / fmaxf(cnF, 1.f);
    r.z = 1.f;
    r.w = 0.f;
    *(float4*)(rowRes + 4 * (size_t)row) = r;     // plain store, no atomics
  }
}

// ---------------- final: tree-reduce per-row results ----------------
__global__ __launch_bounds__(256) void k_final(const float* __restrict__ accf,
    const float* __restrict__ rowRes, float* __restrict__ out){
  const int tid = threadIdx.x;
  float p = 0.f, n = 0.f, c = 0.f;
  for (int i = tid; i < NROW; i += 256){
    float4 r = *(const float4*)(rowRes + 4 * (size_t)i);
    p += r.x; n += r.y; c += r.z;
  }
  p = bfRedF(p); n = bfRedF(n); c = bfRedF(c);
  __shared__ float sb[12];
  const int wav = tid >> 6;
  if ((tid & 63) == 0){ sb[wav] = p; sb[4 + wav] = n; sb[8 + wav] = c; }
  __syncthreads();
  if (tid == 0){
    p = sb[0] + sb[1] + sb[2] + sb[3];
    n = sb[4] + sb[5] + sb[6] + sb[7];
    c = sb[8] + sb[9] + sb[10] + sb[11];
    float posL = 0.f, navL = 0.f;
    if (c > 0.f){ posL = p / c; navL = n / c; }
    out[0] = posL + navL + 0.1f * (accf[0] / (float)(NROW * KDIM));
  }
}

extern "C" void kernel_launch(void* const* d_in, const int* in_sizes, int n_in,
                              void* d_out, int out_size, void* d_ws, size_t ws_size,
                              hipStream_t stream){
  const float* u = (const float*)d_in[0];
  const int* y = (const int*)d_in[1];
  char* ws = (char*)d_ws;
  float* accf = (float*)ws;                        // [0]=qSum
  int* cnt = (int*)(ws + 64);                      // 256 ints
  float* rowRes = (float*)(ws + 4096);             // 6144 * 16 B = 98304 B
  unsigned char* lab = (unsigned char*)(ws + 102400);      // 6144 B
  int* simIdx = (int*)(ws + 108544);               // 200*512 ints = 409600 B
  _Float16* uhswz = (_Float16*)(ws + 518144);      // 1572864 B
  const size_t ibufOff = 518144 + (size_t)NROW * KDIM * 2; // 2091008, 16B aligned
  _Float16* ibuf = (_Float16*)(ws + ibufOff);

  hipMemsetAsync(d_ws, 0, 102400, stream);         // accf + cnt + rowRes
  k_labtanh<<<NROW / 4 + (NROW * 16) / 256, 256, 0, stream>>>(y, lab, cnt, simIdx,
                                                              u, uhswz, accf);

  size_t avail = (ws_size > ibufOff) ? ws_size - ibufOff : 0;
  long maxRows = (long)(avail / ((size_t)NROW * 2));
  maxRows = (maxRows / 128) * 128;
  if (maxRows > NROW) maxRows = NROW;
  if (maxRows < 128) maxRows = 128;

  for (int r0 = 0; r0 < NROW; r0 += (int)maxRows){
    int rows = NROW - r0;
    if (rows > maxRows) rows = (int)maxRows;
    k_mm<<<dim3(48, rows / 128), 256, 0, stream>>>(uhswz, ibuf, r0);
    k_stats<<<rows, 256, 0, stream>>>(ibuf, lab, cnt, simIdx, rowRes, r0);
  }
  k_final<<<1, 256, 0, stream>>>(accf, rowRes, (float*)d_out);
}

// Round 8
// 168.552 us; speedup vs baseline: 1.0563x; 1.0563x over previous
//
#include <hip/hip_runtime.h>
#include <cstdint>

#define NROW 6144
#define KDIM 128
#define NLAB 200
#define C_COEF (-0.28719499063341177f)   /* -ln(99)/16 ; A_COEF = 2 exactly */
#define UBV 64.0f

typedef _Float16 f16x8 __attribute__((ext_vector_type(8)));
typedef _Float16 f16x2 __attribute__((ext_vector_type(2)));
typedef float f32x4 __attribute__((ext_vector_type(4)));
typedef __attribute__((address_space(1))) const void as1c_void;
typedef __attribute__((address_space(3))) void as3_void;

union U8 { f16x8 h; unsigned u[4]; f16x2 p[4]; };
union CV16 { _Float16 h; unsigned short us; };

__device__ __forceinline__ float softplus_f(float x){
  return fmaxf(x, 0.f) + __logf(1.f + __expf(-fabsf(x)));
}
__device__ __forceinline__ float waveRedF(float v){
#pragma unroll
  for (int o = 32; o; o >>= 1) v += __shfl_down(v, o, 64);
  return v;
}
__device__ __forceinline__ float bfRedF(float v){
#pragma unroll
  for (int o = 32; o; o >>= 1) v += __shfl_xor(v, o, 64);
  return v;
}
__device__ __forceinline__ int bfRedI(int v){
#pragma unroll
  for (int o = 32; o; o >>= 1) v += __shfl_xor(v, o, 64);
  return v;
}
__device__ __forceinline__ int bfMaxI(int v){
#pragma unroll
  for (int o = 32; o; o >>= 1){ int x = __shfl_xor(v, o, 64); v = v > x ? v : x; }
  return v;
}
__device__ __forceinline__ float bfMaxF(float v){
#pragma unroll
  for (int o = 32; o; o >>= 1) v = fmaxf(v, __shfl_xor(v, o, 64));
  return v;
}
// sortable key: ascending key == ascending value (f16, no NaN present)
__device__ __forceinline__ float val_of_key(unsigned key){
  unsigned bits = (key & 0x8000u) ? (key ^ 0x8000u) : (key ^ 0xFFFFu);
  CV16 cv; cv.us = (unsigned short)bits;
  return (float)cv.h;
}

// ---------------- fused: labels/member-lists (4 rows/block) | tanh + q-loss ----
__global__ __launch_bounds__(256) void k_labtanh(const int* __restrict__ y,
    unsigned char* __restrict__ lab, int* __restrict__ cnt, int* __restrict__ simIdx,
    const float* __restrict__ u, _Float16* __restrict__ uhswz, float* __restrict__ accf){
  const int bid = blockIdx.x;
  const int tid = threadIdx.x;
  const int NLB = NROW / 4;                        // 1536 label blocks
  if (bid < NLB){                                  // ---- label part: wave per row ----
    const int lane = tid & 63;
    const int row = bid * 4 + (tid >> 6);
    if (lane < NLAB / 4){
      const int4 v = ((const int4*)(y + (size_t)row * NLAB))[lane];
      int t = -1;
      if (v.x != 0) t = 4 * lane;
      if (v.y != 0) t = 4 * lane + 1;
      if (v.z != 0) t = 4 * lane + 2;
      if (v.w != 0) t = 4 * lane + 3;
      if (t >= 0){
        lab[row] = (unsigned char)t;
        int p = atomicAdd(&cnt[t], 1);
        if (p < 512) simIdx[t * 512 + p] = row;
      }
    }
    return;
  }
  // ---- tanh part ----
  const int gid = (bid - NLB) * 256 + tid;
  const int row = gid >> 4;
  const int h = gid & 15;
  const int g = h ^ (row & 7);
  const float* sp = u + (size_t)row * KDIM + g * 8;
  float q = 0.f;
  f16x8 o;
#pragma unroll
  for (int t = 0; t < 8; t++){
    float x = sp[t];
    float e2 = __expf(2.f * x);
    float th = 1.f - 2.f * __builtin_amdgcn_rcpf(e2 + 1.f);  // tanh, ~1e-6 err
    float sg = (th > 0.f) ? 1.f : ((th < 0.f) ? -1.f : 0.f);
    float d = th - sg;
    q += d * d;
    o[t] = (_Float16)th;
  }
  *(f16x8*)(uhswz + (size_t)row * KDIM + h * 8) = o;
  q = waveRedF(q);
  __shared__ float qb[4];
  if ((tid & 63) == 0) qb[tid >> 6] = q;
  __syncthreads();
  if (tid == 0) atomicAdd(&accf[0], qb[0] + qb[1] + qb[2] + qb[3]);
}

// ---------------- inner = uh @ uh^T -> f16 out via LDS-transpose epilogue ----------------
// sym=1 (single-chunk): only bi<=bj tiles computed; off-diagonal tiles also
// emit the mirrored (bj,bi) tile via a second transposed epilogue. Exact:
// MFMA dot order identical for (i,j) and (j,i).
__global__ __launch_bounds__(256) void k_mm(const _Float16* __restrict__ A,
    _Float16* __restrict__ out, int row0, int sym){
  const int bj = blockIdx.x, bi = blockIdx.y;
  if (sym && bi > bj) return;
  __shared__ __align__(16) _Float16 SH[2 * 128 * KDIM];   // 64 KB: As|Bs, reused as Cs
  _Float16* As = SH;
  _Float16* Bs = SH + 128 * KDIM;
  const int tid = threadIdx.x;
  const int wav = tid >> 6, lane = tid & 63;

  const char* Ag = (const char*)(A + (size_t)(row0 + bi * 128) * KDIM);
  const char* Bg = (const char*)(A + (size_t)(bj * 128) * KDIM);
  char* Asb = (char*)As;
  char* Bsb = (char*)Bs;
#pragma unroll
  for (int t = 0; t < 8; t++){
    const int ub = wav * 8192 + t * 1024;
    __builtin_amdgcn_global_load_lds((as1c_void*)(Ag + ub + lane * 16),
                                     (as3_void*)(Asb + ub), 16, 0, 0);
    __builtin_amdgcn_global_load_lds((as1c_void*)(Bg + ub + lane * 16),
                                     (as3_void*)(Bsb + ub), 16, 0, 0);
  }
  __syncthreads();

  const int quad = lane >> 4, l16 = lane & 15;
  const int wm = (wav >> 1) * 64, wn = (wav & 1) * 64;
  f32x4 acc[4][4];
#pragma unroll
  for (int im = 0; im < 4; im++)
#pragma unroll
    for (int in = 0; in < 4; in++)
      acc[im][in] = (f32x4){0.f, 0.f, 0.f, 0.f};

#pragma unroll
  for (int kb = 0; kb < 4; kb++){
    f16x8 af[4], bf[4];
#pragma unroll
    for (int i = 0; i < 4; i++){
      const int m = wm + i * 16 + l16;
      const int gidx = kb * 4 + quad;
      af[i] = *(const f16x8*)(Asb + m * 256 + ((gidx ^ (m & 7)) << 4));
      const int n = wn + i * 16 + l16;
      bf[i] = *(const f16x8*)(Bsb + n * 256 + ((gidx ^ (n & 7)) << 4));
    }
#pragma unroll
    for (int im = 0; im < 4; im++)
#pragma unroll
      for (int in = 0; in < 4; in++)
        acc[im][in] = __builtin_amdgcn_mfma_f32_16x16x32_f16(af[im], bf[in], acc[im][in], 0, 0, 0);
  }
  __syncthreads();                                 // done reading As/Bs

  _Float16* Cs = SH;                               // 128*132*2 = 33792 B
#pragma unroll
  for (int im = 0; im < 4; im++)
#pragma unroll
    for (int in = 0; in < 4; in++)
#pragma unroll
      for (int r = 0; r < 4; r++){
        const int rl = wm + im * 16 + quad * 4 + r;
        const int cl = wn + in * 16 + l16;
        Cs[rl * 132 + cl] = (_Float16)acc[im][in][r];
      }
  __syncthreads();

  _Float16* obase = out + (size_t)(bi * 128) * NROW + (size_t)bj * 128;
  const int s = tid & 15;
#pragma unroll
  for (int i = 0; i < 8; i++){
    const int r = (tid >> 4) + i * 16;
    f16x8 vv = *(const f16x8*)(Cs + r * 132 + s * 8);
    *(f16x8*)(obase + (size_t)r * NROW + s * 8) = vv;
  }

  if (sym && bi != bj){
    __syncthreads();                               // done reading Cs (pass 1)
    // rebuild transposed: CsT[cl][rl] = C[rl][cl]
#pragma unroll
    for (int im = 0; im < 4; im++)
#pragma unroll
      for (int in = 0; in < 4; in++)
#pragma unroll
        for (int r = 0; r < 4; r++){
          const int rl = wm + im * 16 + quad * 4 + r;
          const int cl = wn + in * 16 + l16;
          Cs[cl * 132 + rl] = (_Float16)acc[im][in][r];
        }
    __syncthreads();
    _Float16* obase2 = out + (size_t)(bj * 128) * NROW + (size_t)bi * 128;
#pragma unroll
    for (int i = 0; i < 8; i++){
      const int r = (tid >> 4) + i * 16;
      f16x8 vv = *(const f16x8*)(Cs + r * 132 + s * 8);
      *(f16x8*)(obase2 + (size_t)r * NROW + s * 8) = vv;
    }
  }
}

// ---------------- per-row stats + loss: ONE WAVE PER ROW, 2-level radix select ----
// (r6 structure — proven fastest.) x4-replicated wave-private histograms, maskless
// loss sweep, gathered sim lists, no __syncthreads. Sweeps unrolled x2 for MLP.
__global__ __launch_bounds__(256) void k_stats(const _Float16* __restrict__ buf,
    const unsigned char* __restrict__ lab, const int* __restrict__ cnt,
    const int* __restrict__ simIdx, float* __restrict__ rowRes, int row0){
  __shared__ int   histS[4][1028];   // 4 waves x (4 copies x 257) = 16448 B
  __shared__ float simvS[4][512];    // 8192 B
  const int tid = threadIdx.x;
  const int lane = tid & 63;
  const int wav = tid >> 6;
  const int lrow = blockIdx.x * 4 + wav;          // chunk-local row
  const int row = row0 + lrow;
  const int myl = lab[row];
  const int n_sim = cnt[myl];
  const int n_dis = NROW - n_sim;
  if (n_dis == 0 || n_sim == 0) return;           // wave-uniform exit (rowRes stays 0)
  const int k1 = n_dis - (n_dis * 9) / 10;        // tail count (top-10% dissimilar)
  const int k2 = n_sim - (n_sim * 9) / 10;        // head count (bottom-10% similar)
  const int ns = (n_sim < 512) ? n_sim : 512;

  int*   hist = histS[wav];
  int*   myh  = hist + (lane >> 4) * 257;         // per-16-lane-group private copy
  float* simv = simvS[wav];
#pragma unroll
  for (int r = 0; r < 4; r++) *(int4*)&hist[(lane + 64 * r) * 4] = make_int4(0, 0, 0, 0);
  if (lane == 0) *(int4*)&hist[1024] = make_int4(0, 0, 0, 0);

  const f16x8* src = (const f16x8*)(buf + (size_t)lrow * NROW);
  const _Float16* srcs = buf + (size_t)lrow * NROW;

  // ---- P0: total sum + level-1 (key high byte) histogram over ALL elements ----
  float sumAll = 0.f;
  const f16x2 ones = (f16x2){(_Float16)1.f, (_Float16)1.f};
#pragma unroll 2
  for (int it = 0; it < 12; ++it){
    U8 x; x.h = src[it * 64 + lane];
#pragma unroll
    for (int k = 0; k < 4; k++){
      unsigned wv = x.u[k];
      unsigned m = (wv >> 15) & 0x00010001u;
      unsigned key2 = wv ^ 0x80008000u ^ (m * 0x7FFFu);   // two sortable u16 keys
      atomicAdd(&myh[(key2 >> 8) & 0xFFu], 1);
      atomicAdd(&myh[key2 >> 24], 1);
#if __has_builtin(__builtin_amdgcn_fdot2)
      sumAll = __builtin_amdgcn_fdot2(x.p[k], ones, sumAll, false);
#else
      sumAll += (float)x.h[2 * k] + (float)x.h[2 * k + 1];
#endif
    }
  }

  // ---- gather sim values via member list; subtract from level-1 histogram ----
  float sumS = 0.f;
  for (int t = lane; t < ns; t += 64){
    int idx = simIdx[myl * 512 + t];
    CV16 cv; cv.h = srcs[idx];
    unsigned bits = (unsigned)cv.us;
    unsigned key = bits ^ 0x8000u ^ ((bits >> 15) * 0x7FFFu);
    float v = (float)cv.h;
    simv[t] = v; sumS += v;
    atomicAdd(&myh[key >> 8], -1);
  }
  sumAll = bfRedF(sumAll);
  sumS = bfRedF(sumS);
  const float sumD = sumAll - sumS;

  // ---- level-1 select: pivot high-byte bucket (descending suffix scan) ----
  int cArr[4];
#pragma unroll
  for (int d = 0; d < 4; d++){
    const int b = 4 * lane + d;
    cArr[d] = hist[b] + hist[257 + b] + hist[514 + b] + hist[771 + b];
  }
  int part = cArr[0] + cArr[1] + cArr[2] + cArr[3];
  int suf = part;
#pragma unroll
  for (int o = 1; o < 64; o <<= 1){
    int x = __shfl_down(suf, o, 64);
    if (lane + o < 64) suf += x;
  }
  int cum = suf - part;                           // count in buckets above group
  int encB = -1, krF = 0;
#pragma unroll
  for (int d = 3; d >= 0; --d){
    int cd = cArr[d];
    if (k1 > cum && k1 <= cum + cd){ encB = 4 * lane + d; krF = k1 - cum; }
    cum += cd;
  }
  const int hbStar = bfMaxI(encB);
  const int kr1 = bfMaxI(krF);                    // rank within pivot bucket (from top)

#pragma unroll
  for (int r = 0; r < 4; r++) *(int4*)&hist[(lane + 64 * r) * 4] = make_int4(0, 0, 0, 0);
  if (lane == 0) *(int4*)&hist[1024] = make_int4(0, 0, 0, 0);

  // ---- pass B: above-bucket sum + level-2 (low byte) histogram, ALL elements ----
  float sAb = 0.f;
#pragma unroll 2
  for (int it = 0; it < 12; ++it){
    U8 x; x.h = src[it * 64 + lane];
#pragma unroll
    for (int k = 0; k < 4; k++){
      unsigned wv = x.u[k];
      unsigned m = (wv >> 15) & 0x00010001u;
      unsigned key2 = wv ^ 0x80008000u ^ (m * 0x7FFFu);
      int hbLo = (key2 >> 8) & 0xFF;
      int hbHi = key2 >> 24;
      if (hbLo > hbStar) sAb += (float)x.h[2 * k];
      else if (hbLo == hbStar) atomicAdd(&myh[key2 & 0xFFu], 1);
      if (hbHi > hbStar) sAb += (float)x.h[2 * k + 1];
      else if (hbHi == hbStar) atomicAdd(&myh[(key2 >> 16) & 0xFFu], 1);
    }
  }
  // subtract gathered sims from sAb / level-2 histogram
  for (int t = lane; t < ns; t += 64){
    float v = simv[t];
    CV16 cv; cv.h = (_Float16)v;                  // exact roundtrip (v came from f16)
    unsigned bits = (unsigned)cv.us;
    unsigned key = bits ^ 0x8000u ^ ((bits >> 15) * 0x7FFFu);
    int hb = (int)(key >> 8);
    if (hb > hbStar) sAb -= v;
    else if (hb == hbStar) atomicAdd(&myh[key & 0xFFu], -1);
  }
  sAb = bfRedF(sAb);

  // ---- level-2 select: exact pivot value + above-pivot sum from counts ----
  int c2[4];
#pragma unroll
  for (int d = 0; d < 4; d++){
    const int b = 4 * lane + d;
    c2[d] = hist[b] + hist[257 + b] + hist[514 + b] + hist[771 + b];
  }
  part = c2[0] + c2[1] + c2[2] + c2[3];
  suf = part;
#pragma unroll
  for (int o = 1; o < 64; o <<= 1){
    int x = __shfl_down(suf, o, 64);
    if (lane + o < 64) suf += x;
  }
  cum = suf - part;
  int encL = -1, g2F = 0;
#pragma unroll
  for (int d = 3; d >= 0; --d){
    int cd = c2[d];
    if (kr1 > cum && kr1 <= cum + cd){ encL = 4 * lane + d; g2F = cum; }
    cum += cd;
  }
  const int lbStar = bfMaxI(encL);
  const int gt2 = bfMaxI(g2F);                    // strictly-above count in bucket
  float sumIn = 0.f;
#pragma unroll
  for (int d = 0; d < 4; d++){
    int lb = 4 * lane + d;
    if (lb > lbStar) sumIn += (float)c2[d] * val_of_key((unsigned)((hbStar << 8) | lb));
  }
  sumIn = bfRedF(sumIn);
  const float piv = val_of_key((unsigned)((hbStar << 8) | lbStar));
  const float dSum = sAb + sumIn + (float)(kr1 - gt2) * piv;

  // ---- sMin: k2-th smallest similar (exact rank-count on wave-private list) ----
  float fpiv2 = -3e38f; int flt = 0;
  for (int t = lane; t < ns; t += 64){
    float vt = simv[t];
    int lt = 0, eq = 0;
    for (int j = 0; j < ns; j++){
      float vj = simv[j];
      lt += (vj < vt); eq += (vj == vt);
    }
    if (lt < k2 && k2 <= lt + eq){ fpiv2 = vt; flt = lt; }
  }
  const float piv2 = bfMaxF(fpiv2);
  const int ltS = bfMaxI(flt);
  float slt = 0.f;
  for (int t = lane; t < ns; t += 64){
    float v = simv[t];
    if (v < piv2) slt += v;
  }
  slt = bfRedF(slt);
  const float sSum = slt + (float)(k2 - ltS) * piv2;

  // ---- BP / BPd (computed redundantly by all lanes) ----
  const float meanS  = fminf(fmaxf(sumS / fmaxf((float)n_sim, 1.f), 0.f), UBV);
  const float meanDS = fminf(fmaxf(sumD / fmaxf((float)n_dis, 1.f), 0.f), UBV);
  const float dMax   = fminf(fmaxf(dSum / fmaxf((float)k1, 1.f), 0.f), UBV);
  const float sMin   = fminf(fmaxf(sSum / fmaxf((float)k2, 1.f), 0.f), UBV);
  const float BP  = meanS - (UBV - meanS) / UBV * fabsf(meanS - dMax);
  const float BPd = meanDS + meanDS / UBV * fabsf(meanDS - sMin);

  // ---- loss pass: MASKLESS dissimilar sweep (subtract sims after) ----
  float an = 0.f; int ties = 0;
#pragma unroll 2
  for (int it = 0; it < 12; ++it){
    f16x8 h8 = src[it * 64 + lane];
#pragma unroll
    for (int e = 0; e < 8; e++){
      float v = (float)h8[e];
      float dcd = v - BPd;                        // sign-exact; ==0 iff v==BPd
      float f = ((dcd < 0.f) ? C_COEF : 2.f * C_COEF) * dcd;
      an += softplus_f(-f);
      ties += (dcd == 0.f);
    }
  }
  // sim-side corrections (≤ ~31 values, 1 iteration typically)
  float spSim = 0.f; int tiesSim = 0;
  float ap = 0.f, cp = 0.f;
  for (int t = lane; t < ns; t += 64){
    float v = simv[t];
    float dcd = v - BPd;
    if (dcd == 0.f) tiesSim++;
    else {
      float f = ((dcd < 0.f) ? C_COEF : 2.f * C_COEF) * dcd;
      spSim += softplus_f(-f);
    }
    if (v != BP){
      float dc = v - BP;
      float f = (v > BP) ? C_COEF * dc : (2.f * C_COEF) * dc;
      ap += softplus_f(f); cp += 1.f;
    }
  }
  an = bfRedF(an); spSim = bfRedF(spSim);
  const int tiesT = bfRedI(ties);
  const int tiesSimT = bfRedI(tiesSim);
  ap = bfRedF(ap); cp = bfRedF(cp);
  if (lane == 0){
    const float L = __logf(1.f + __expf(-0.f));   // == value added per tie in sweep
    float anF = an - (float)tiesT * L - spSim;
    float cnF = (float)(n_dis - (tiesT - tiesSimT));
    float4 r;
    r.x = ap / fmaxf(cp, 1.f);
    r.y = anF / fmaxf(cnF, 1.f);
    r.z = 1.f;
    r.w = 0.f;
    *(float4*)(rowRes + 4 * (size_t)row) = r;     // plain store, no atomics
  }
}

// ---------------- final: tree-reduce per-row results ----------------
__global__ __launch_bounds__(256) void k_final(const float* __restrict__ accf,
    const float* __restrict__ rowRes, float* __restrict__ out){
  const int tid = threadIdx.x;
  float p = 0.f, n = 0.f, c = 0.f;
  for (int i = tid; i < NROW; i += 256){
    float4 r = *(const float4*)(rowRes + 4 * (size_t)i);
    p += r.x; n += r.y; c += r.z;
  }
  p = bfRedF(p); n = bfRedF(n); c = bfRedF(c);
  __shared__ float sb[12];
  const int wav = tid >> 6;
  if ((tid & 63) == 0){ sb[wav] = p; sb[4 + wav] = n; sb[8 + wav] = c; }
  __syncthreads();
  if (tid == 0){
    p = sb[0] + sb[1] + sb[2] + sb[3];
    n = sb[4] + sb[5] + sb[6] + sb[7];
    c = sb[8] + sb[9] + sb[10] + sb[11];
    float posL = 0.f, navL = 0.f;
    if (c > 0.f){ posL = p / c; navL = n / c; }
    out[0] = posL + navL + 0.1f * (accf[0] / (float)(NROW * KDIM));
  }
}

extern "C" void kernel_launch(void* const* d_in, const int* in_sizes, int n_in,
                              void* d_out, int out_size, void* d_ws, size_t ws_size,
                              hipStream_t stream){
  const float* u = (const float*)d_in[0];
  const int* y = (const int*)d_in[1];
  char* ws = (char*)d_ws;
  float* accf = (float*)ws;                        // [0]=qSum
  int* cnt = (int*)(ws + 64);                      // 256 ints
  float* rowRes = (float*)(ws + 4096);             // 6144 * 16 B = 98304 B
  unsigned char* lab = (unsigned char*)(ws + 102400);      // 6144 B
  int* simIdx = (int*)(ws + 108544);               // 200*512 ints = 409600 B
  _Float16* uhswz = (_Float16*)(ws + 518144);      // 1572864 B
  const size_t ibufOff = 518144 + (size_t)NROW * KDIM * 2; // 2091008, 16B aligned
  _Float16* ibuf = (_Float16*)(ws + ibufOff);

  hipMemsetAsync(d_ws, 0, 102400, stream);         // accf + cnt + rowRes
  k_labtanh<<<NROW / 4 + (NROW * 16) / 256, 256, 0, stream>>>(y, lab, cnt, simIdx,
                                                              u, uhswz, accf);

  size_t avail = (ws_size > ibufOff) ? ws_size - ibufOff : 0;
  long maxRows = (long)(avail / ((size_t)NROW * 2));
  maxRows = (maxRows / 128) * 128;
  if (maxRows > NROW) maxRows = NROW;
  if (maxRows < 128) maxRows = 128;

  for (int r0 = 0; r0 < NROW; r0 += (int)maxRows){
    int rows = NROW - r0;
    if (rows > maxRows) rows = (int)maxRows;
    const int sym = (rows == NROW) ? 1 : 0;        // symmetric path needs full matrix
    k_mm<<<dim3(48, rows / 128), 256, 0, stream>>>(uhswz, ibuf, r0, sym);
    k_stats<<<rows / 4, 256, 0, stream>>>(ibuf, lab, cnt, simIdx, rowRes, r0);
  }
  k_final<<<1, 256, 0, stream>>>(accf, rowRes, (float*)d_out);
}

// Round 9
// 165.103 us; speedup vs baseline: 1.0784x; 1.0209x over previous
//
#include <hip/hip_runtime.h>
#include <cstdint>

#define NROW 6144
#define KDIM 128
#define NLAB 200
#define C_COEF (-0.28719499063341177f)   /* -ln(99)/16 ; A_COEF = 2 exactly */
#define UBV 64.0f

typedef _Float16 f16x8 __attribute__((ext_vector_type(8)));
typedef _Float16 f16x2 __attribute__((ext_vector_type(2)));
typedef float f32x4 __attribute__((ext_vector_type(4)));
typedef __attribute__((address_space(1))) const void as1c_void;
typedef __attribute__((address_space(3))) void as3_void;

union U8 { f16x8 h; unsigned u[4]; f16x2 p[4]; };
union CV16 { _Float16 h; unsigned short us; };

__device__ __forceinline__ float softplus_f(float x){
  return fmaxf(x, 0.f) + __logf(1.f + __expf(-fabsf(x)));
}
__device__ __forceinline__ float waveRedF(float v){
#pragma unroll
  for (int o = 32; o; o >>= 1) v += __shfl_down(v, o, 64);
  return v;
}
__device__ __forceinline__ float bfRedF(float v){
#pragma unroll
  for (int o = 32; o; o >>= 1) v += __shfl_xor(v, o, 64);
  return v;
}
__device__ __forceinline__ int bfRedI(int v){
#pragma unroll
  for (int o = 32; o; o >>= 1) v += __shfl_xor(v, o, 64);
  return v;
}
__device__ __forceinline__ int bfMaxI(int v){
#pragma unroll
  for (int o = 32; o; o >>= 1){ int x = __shfl_xor(v, o, 64); v = v > x ? v : x; }
  return v;
}
__device__ __forceinline__ float bfMaxF(float v){
#pragma unroll
  for (int o = 32; o; o >>= 1) v = fmaxf(v, __shfl_xor(v, o, 64));
  return v;
}
// sortable key: ascending key == ascending value (f16, no NaN present)
__device__ __forceinline__ float val_of_key(unsigned key){
  unsigned bits = (key & 0x8000u) ? (key ^ 0x8000u) : (key ^ 0xFFFFu);
  CV16 cv; cv.us = (unsigned short)bits;
  return (float)cv.h;
}

// ---------------- fused: labels/member-lists (4 rows/block) | tanh + q-loss ----
__global__ __launch_bounds__(256) void k_labtanh(const int* __restrict__ y,
    unsigned char* __restrict__ lab, int* __restrict__ cnt, int* __restrict__ simIdx,
    const float* __restrict__ u, _Float16* __restrict__ uhswz, float* __restrict__ accf){
  const int bid = blockIdx.x;
  const int tid = threadIdx.x;
  const int NLB = NROW / 4;                        // 1536 label blocks
  if (bid < NLB){                                  // ---- label part: wave per row ----
    const int lane = tid & 63;
    const int row = bid * 4 + (tid >> 6);
    if (lane < NLAB / 4){
      const int4 v = ((const int4*)(y + (size_t)row * NLAB))[lane];
      int t = -1;
      if (v.x != 0) t = 4 * lane;
      if (v.y != 0) t = 4 * lane + 1;
      if (v.z != 0) t = 4 * lane + 2;
      if (v.w != 0) t = 4 * lane + 3;
      if (t >= 0){
        lab[row] = (unsigned char)t;
        int p = atomicAdd(&cnt[t], 1);
        if (p < 512) simIdx[t * 512 + p] = row;
      }
    }
    return;
  }
  // ---- tanh part ----
  const int gid = (bid - NLB) * 256 + tid;
  const int row = gid >> 4;
  const int h = gid & 15;
  const int g = h ^ (row & 7);
  const float* sp = u + (size_t)row * KDIM + g * 8;
  float q = 0.f;
  f16x8 o;
#pragma unroll
  for (int t = 0; t < 8; t++){
    float x = sp[t];
    float e2 = __expf(2.f * x);
    float th = 1.f - 2.f * __builtin_amdgcn_rcpf(e2 + 1.f);  // tanh, ~1e-6 err
    float sg = (th > 0.f) ? 1.f : ((th < 0.f) ? -1.f : 0.f);
    float d = th - sg;
    q += d * d;
    o[t] = (_Float16)th;
  }
  *(f16x8*)(uhswz + (size_t)row * KDIM + h * 8) = o;
  q = waveRedF(q);
  __shared__ float qb[4];
  if ((tid & 63) == 0) qb[tid >> 6] = q;
  __syncthreads();
  if (tid == 0) atomicAdd(&accf[0], qb[0] + qb[1] + qb[2] + qb[3]);
}

// ---------------- inner = uh @ uh^T -> f16, 512-thread blocks (16 waves/CU) ----
// sym=1: triangular grid (1176 blocks), bi<=bj decoded from linear blockIdx.x;
// off-diagonal tiles also emit the mirrored tile via a transposed epilogue
// (bit-exact: per-element dot order identical under operand swap).
// Diagonal tiles stage only the A panel (Bs = As).
__global__ __launch_bounds__(512) void k_mm(const _Float16* __restrict__ A,
    _Float16* __restrict__ out, int row0, int sym){
  int bi, bj;
  if (sym){
    int t = blockIdx.x;                            // triangular decode, bj in [bi,48)
    int b = 0, off = 0;
    while (t >= off + (48 - b)){ off += 48 - b; b++; }
    bi = b; bj = b + (t - off);
  } else {
    bi = blockIdx.y; bj = blockIdx.x;
  }
  __shared__ __align__(16) _Float16 SH[2 * 128 * KDIM];   // 64 KB: As|Bs, reused as Cs
  const int tid = threadIdx.x;
  const int wav = tid >> 6, lane = tid & 63;
  const bool diag = sym && (bi == bj);

  const char* Ag = (const char*)(A + (size_t)(row0 + bi * 128) * KDIM);
  const char* Bg = (const char*)(A + (size_t)(bj * 128) * KDIM);
  char* Asb = (char*)SH;
  char* Bsb = diag ? Asb : (char*)(SH + 128 * KDIM);
#pragma unroll
  for (int t = 0; t < 4; t++){
    const int ub = wav * 4096 + t * 1024;          // 8 waves x 4 KB = 32 KB panel
    __builtin_amdgcn_global_load_lds((as1c_void*)(Ag + ub + lane * 16),
                                     (as3_void*)(Asb + ub), 16, 0, 0);
    if (!diag)
      __builtin_amdgcn_global_load_lds((as1c_void*)(Bg + ub + lane * 16),
                                       (as3_void*)(Bsb + ub), 16, 0, 0);
  }
  __syncthreads();

  const int quad = lane >> 4, l16 = lane & 15;
  const int wm = (wav >> 2) * 64, wn = (wav & 3) * 32;   // 64x32 per wave
  f32x4 acc[4][2];
#pragma unroll
  for (int im = 0; im < 4; im++)
#pragma unroll
    for (int in = 0; in < 2; in++)
      acc[im][in] = (f32x4){0.f, 0.f, 0.f, 0.f};

#pragma unroll
  for (int kb = 0; kb < 4; kb++){
    f16x8 af[4], bf[2];
    const int gidx = kb * 4 + quad;
#pragma unroll
    for (int i = 0; i < 4; i++){
      const int m = wm + i * 16 + l16;
      af[i] = *(const f16x8*)(Asb + m * 256 + ((gidx ^ (m & 7)) << 4));
    }
#pragma unroll
    for (int j = 0; j < 2; j++){
      const int n = wn + j * 16 + l16;
      bf[j] = *(const f16x8*)(Bsb + n * 256 + ((gidx ^ (n & 7)) << 4));
    }
#pragma unroll
    for (int im = 0; im < 4; im++)
#pragma unroll
      for (int in = 0; in < 2; in++)
        acc[im][in] = __builtin_amdgcn_mfma_f32_16x16x32_f16(af[im], bf[in], acc[im][in], 0, 0, 0);
  }
  __syncthreads();                                 // done reading As/Bs

  _Float16* Cs = (_Float16*)SH;                    // 128*132*2 = 33792 B
#pragma unroll
  for (int im = 0; im < 4; im++)
#pragma unroll
    for (int in = 0; in < 2; in++)
#pragma unroll
      for (int r = 0; r < 4; r++){
        const int rl = wm + im * 16 + quad * 4 + r;
        const int cl = wn + in * 16 + l16;
        Cs[rl * 132 + cl] = (_Float16)acc[im][in][r];
      }
  __syncthreads();

  _Float16* obase = out + (size_t)(bi * 128) * NROW + (size_t)bj * 128;
  const int s = tid & 15;
  const int rb = tid >> 4;                         // 0..31
#pragma unroll
  for (int i = 0; i < 4; i++){
    const int r = rb + i * 32;
    f16x8 vv = *(const f16x8*)(Cs + r * 132 + s * 8);
    *(f16x8*)(obase + (size_t)r * NROW + s * 8) = vv;
  }

  if (sym && bi != bj){
    __syncthreads();                               // done reading Cs (pass 1)
#pragma unroll
    for (int im = 0; im < 4; im++)
#pragma unroll
      for (int in = 0; in < 2; in++)
#pragma unroll
        for (int r = 0; r < 4; r++){
          const int rl = wm + im * 16 + quad * 4 + r;
          const int cl = wn + in * 16 + l16;
          Cs[cl * 132 + rl] = (_Float16)acc[im][in][r];   // transposed
        }
    __syncthreads();
    _Float16* obase2 = out + (size_t)(bj * 128) * NROW + (size_t)bi * 128;
#pragma unroll
    for (int i = 0; i < 4; i++){
      const int r = rb + i * 32;
      f16x8 vv = *(const f16x8*)(Cs + r * 132 + s * 8);
      *(f16x8*)(obase2 + (size_t)r * NROW + s * 8) = vv;
    }
  }
}

// ---------------- per-row stats + loss: ONE WAVE PER ROW, 2-level radix select ----
// (r8 kernel, unchanged — proven 65.2 us.)
__global__ __launch_bounds__(256) void k_stats(const _Float16* __restrict__ buf,
    const unsigned char* __restrict__ lab, const int* __restrict__ cnt,
    const int* __restrict__ simIdx, float* __restrict__ rowRes, int row0){
  __shared__ int   histS[4][1028];   // 4 waves x (4 copies x 257) = 16448 B
  __shared__ float simvS[4][512];    // 8192 B
  const int tid = threadIdx.x;
  const int lane = tid & 63;
  const int wav = tid >> 6;
  const int lrow = blockIdx.x * 4 + wav;          // chunk-local row
  const int row = row0 + lrow;
  const int myl = lab[row];
  const int n_sim = cnt[myl];
  const int n_dis = NROW - n_sim;
  if (n_dis == 0 || n_sim == 0) return;           // wave-uniform exit (rowRes stays 0)
  const int k1 = n_dis - (n_dis * 9) / 10;        // tail count (top-10% dissimilar)
  const int k2 = n_sim - (n_sim * 9) / 10;        // head count (bottom-10% similar)
  const int ns = (n_sim < 512) ? n_sim : 512;

  int*   hist = histS[wav];
  int*   myh  = hist + (lane >> 4) * 257;         // per-16-lane-group private copy
  float* simv = simvS[wav];
#pragma unroll
  for (int r = 0; r < 4; r++) *(int4*)&hist[(lane + 64 * r) * 4] = make_int4(0, 0, 0, 0);
  if (lane == 0) *(int4*)&hist[1024] = make_int4(0, 0, 0, 0);

  const f16x8* src = (const f16x8*)(buf + (size_t)lrow * NROW);
  const _Float16* srcs = buf + (size_t)lrow * NROW;

  // ---- P0: total sum + level-1 (key high byte) histogram over ALL elements ----
  float sumAll = 0.f;
  const f16x2 ones = (f16x2){(_Float16)1.f, (_Float16)1.f};
#pragma unroll 2
  for (int it = 0; it < 12; ++it){
    U8 x; x.h = src[it * 64 + lane];
#pragma unroll
    for (int k = 0; k < 4; k++){
      unsigned wv = x.u[k];
      unsigned m = (wv >> 15) & 0x00010001u;
      unsigned key2 = wv ^ 0x80008000u ^ (m * 0x7FFFu);   // two sortable u16 keys
      atomicAdd(&myh[(key2 >> 8) & 0xFFu], 1);
      atomicAdd(&myh[key2 >> 24], 1);
#if __has_builtin(__builtin_amdgcn_fdot2)
      sumAll = __builtin_amdgcn_fdot2(x.p[k], ones, sumAll, false);
#else
      sumAll += (float)x.h[2 * k] + (float)x.h[2 * k + 1];
#endif
    }
  }

  // ---- gather sim values via member list; subtract from level-1 histogram ----
  float sumS = 0.f;
  for (int t = lane; t < ns; t += 64){
    int idx = simIdx[myl * 512 + t];
    CV16 cv; cv.h = srcs[idx];
    unsigned bits = (unsigned)cv.us;
    unsigned key = bits ^ 0x8000u ^ ((bits >> 15) * 0x7FFFu);
    float v = (float)cv.h;
    simv[t] = v; sumS += v;
    atomicAdd(&myh[key >> 8], -1);
  }
  sumAll = bfRedF(sumAll);
  sumS = bfRedF(sumS);
  const float sumD = sumAll - sumS;

  // ---- level-1 select: pivot high-byte bucket (descending suffix scan) ----
  int cArr[4];
#pragma unroll
  for (int d = 0; d < 4; d++){
    const int b = 4 * lane + d;
    cArr[d] = hist[b] + hist[257 + b] + hist[514 + b] + hist[771 + b];
  }
  int part = cArr[0] + cArr[1] + cArr[2] + cArr[3];
  int suf = part;
#pragma unroll
  for (int o = 1; o < 64; o <<= 1){
    int x = __shfl_down(suf, o, 64);
    if (lane + o < 64) suf += x;
  }
  int cum = suf - part;                           // count in buckets above group
  int encB = -1, krF = 0;
#pragma unroll
  for (int d = 3; d >= 0; --d){
    int cd = cArr[d];
    if (k1 > cum && k1 <= cum + cd){ encB = 4 * lane + d; krF = k1 - cum; }
    cum += cd;
  }
  const int hbStar = bfMaxI(encB);
  const int kr1 = bfMaxI(krF);                    // rank within pivot bucket (from top)

#pragma unroll
  for (int r = 0; r < 4; r++) *(int4*)&hist[(lane + 64 * r) * 4] = make_int4(0, 0, 0, 0);
  if (lane == 0) *(int4*)&hist[1024] = make_int4(0, 0, 0, 0);

  // ---- pass B: above-bucket sum + level-2 (low byte) histogram, ALL elements ----
  float sAb = 0.f;
#pragma unroll 2
  for (int it = 0; it < 12; ++it){
    U8 x; x.h = src[it * 64 + lane];
#pragma unroll
    for (int k = 0; k < 4; k++){
      unsigned wv = x.u[k];
      unsigned m = (wv >> 15) & 0x00010001u;
      unsigned key2 = wv ^ 0x80008000u ^ (m * 0x7FFFu);
      int hbLo = (key2 >> 8) & 0xFF;
      int hbHi = key2 >> 24;
      if (hbLo > hbStar) sAb += (float)x.h[2 * k];
      else if (hbLo == hbStar) atomicAdd(&myh[key2 & 0xFFu], 1);
      if (hbHi > hbStar) sAb += (float)x.h[2 * k + 1];
      else if (hbHi == hbStar) atomicAdd(&myh[(key2 >> 16) & 0xFFu], 1);
    }
  }
  // subtract gathered sims from sAb / level-2 histogram
  for (int t = lane; t < ns; t += 64){
    float v = simv[t];
    CV16 cv; cv.h = (_Float16)v;                  // exact roundtrip (v came from f16)
    unsigned bits = (unsigned)cv.us;
    unsigned key = bits ^ 0x8000u ^ ((bits >> 15) * 0x7FFFu);
    int hb = (int)(key >> 8);
    if (hb > hbStar) sAb -= v;
    else if (hb == hbStar) atomicAdd(&myh[key & 0xFFu], -1);
  }
  sAb = bfRedF(sAb);

  // ---- level-2 select: exact pivot value + above-pivot sum from counts ----
  int c2[4];
#pragma unroll
  for (int d = 0; d < 4; d++){
    const int b = 4 * lane + d;
    c2[d] = hist[b] + hist[257 + b] + hist[514 + b] + hist[771 + b];
  }
  part = c2[0] + c2[1] + c2[2] + c2[3];
  suf = part;
#pragma unroll
  for (int o = 1; o < 64; o <<= 1){
    int x = __shfl_down(suf, o, 64);
    if (lane + o < 64) suf += x;
  }
  cum = suf - part;
  int encL = -1, g2F = 0;
#pragma unroll
  for (int d = 3; d >= 0; --d){
    int cd = c2[d];
    if (kr1 > cum && kr1 <= cum + cd){ encL = 4 * lane + d; g2F = cum; }
    cum += cd;
  }
  const int lbStar = bfMaxI(encL);
  const int gt2 = bfMaxI(g2F);                    // strictly-above count in bucket
  float sumIn = 0.f;
#pragma unroll
  for (int d = 0; d < 4; d++){
    int lb = 4 * lane + d;
    if (lb > lbStar) sumIn += (float)c2[d] * val_of_key((unsigned)((hbStar << 8) | lb));
  }
  sumIn = bfRedF(sumIn);
  const float piv = val_of_key((unsigned)((hbStar << 8) | lbStar));
  const float dSum = sAb + sumIn + (float)(kr1 - gt2) * piv;

  // ---- sMin: k2-th smallest similar (exact rank-count on wave-private list) ----
  float fpiv2 = -3e38f; int flt = 0;
  for (int t = lane; t < ns; t += 64){
    float vt = simv[t];
    int lt = 0, eq = 0;
    for (int j = 0; j < ns; j++){
      float vj = simv[j];
      lt += (vj < vt); eq += (vj == vt);
    }
    if (lt < k2 && k2 <= lt + eq){ fpiv2 = vt; flt = lt; }
  }
  const float piv2 = bfMaxF(fpiv2);
  const int ltS = bfMaxI(flt);
  float slt = 0.f;
  for (int t = lane; t < ns; t += 64){
    float v = simv[t];
    if (v < piv2) slt += v;
  }
  slt = bfRedF(slt);
  const float sSum = slt + (float)(k2 - ltS) * piv2;

  // ---- BP / BPd (computed redundantly by all lanes) ----
  const float meanS  = fminf(fmaxf(sumS / fmaxf((float)n_sim, 1.f), 0.f), UBV);
  const float meanDS = fminf(fmaxf(sumD / fmaxf((float)n_dis, 1.f), 0.f), UBV);
  const float dMax   = fminf(fmaxf(dSum / fmaxf((float)k1, 1.f), 0.f), UBV);
  const float sMin   = fminf(fmaxf(sSum / fmaxf((float)k2, 1.f), 0.f), UBV);
  const float BP  = meanS - (UBV - meanS) / UBV * fabsf(meanS - dMax);
  const float BPd = meanDS + meanDS / UBV * fabsf(meanDS - sMin);

  // ---- loss pass: MASKLESS dissimilar sweep (subtract sims after) ----
  float an = 0.f; int ties = 0;
#pragma unroll 2
  for (int it = 0; it < 12; ++it){
    f16x8 h8 = src[it * 64 + lane];
#pragma unroll
    for (int e = 0; e < 8; e++){
      float v = (float)h8[e];
      float dcd = v - BPd;                        // sign-exact; ==0 iff v==BPd
      float f = ((dcd < 0.f) ? C_COEF : 2.f * C_COEF) * dcd;
      an += softplus_f(-f);
      ties += (dcd == 0.f);
    }
  }
  // sim-side corrections (≤ ~31 values, 1 iteration typically)
  float spSim = 0.f; int tiesSim = 0;
  float ap = 0.f, cp = 0.f;
  for (int t = lane; t < ns; t += 64){
    float v = simv[t];
    float dcd = v - BPd;
    if (dcd == 0.f) tiesSim++;
    else {
      float f = ((dcd < 0.f) ? C_COEF : 2.f * C_COEF) * dcd;
      spSim += softplus_f(-f);
    }
    if (v != BP){
      float dc = v - BP;
      float f = (v > BP) ? C_COEF * dc : (2.f * C_COEF) * dc;
      ap += softplus_f(f); cp += 1.f;
    }
  }
  an = bfRedF(an); spSim = bfRedF(spSim);
  const int tiesT = bfRedI(ties);
  const int tiesSimT = bfRedI(tiesSim);
  ap = bfRedF(ap); cp = bfRedF(cp);
  if (lane == 0){
    const float L = __logf(1.f + __expf(-0.f));   // == value added per tie in sweep
    float anF = an - (float)tiesT * L - spSim;
    float cnF = (float)(n_dis - (tiesT - tiesSimT));
    float4 r;
    r.x = ap / fmaxf(cp, 1.f);
    r.y = anF / fmaxf(cnF, 1.f);
    r.z = 1.f;
    r.w = 0.f;
    *(float4*)(rowRes + 4 * (size_t)row) = r;     // plain store, no atomics
  }
}

// ---------------- final: tree-reduce per-row results ----------------
__global__ __launch_bounds__(256) void k_final(const float* __restrict__ accf,
    const float* __restrict__ rowRes, float* __restrict__ out){
  const int tid = threadIdx.x;
  float p = 0.f, n = 0.f, c = 0.f;
  for (int i = tid; i < NROW; i += 256){
    float4 r = *(const float4*)(rowRes + 4 * (size_t)i);
    p += r.x; n += r.y; c += r.z;
  }
  p = bfRedF(p); n = bfRedF(n); c = bfRedF(c);
  __shared__ float sb[12];
  const int wav = tid >> 6;
  if ((tid & 63) == 0){ sb[wav] = p; sb[4 + wav] = n; sb[8 + wav] = c; }
  __syncthreads();
  if (tid == 0){
    p = sb[0] + sb[1] + sb[2] + sb[3];
    n = sb[4] + sb[5] + sb[6] + sb[7];
    c = sb[8] + sb[9] + sb[10] + sb[11];
    float posL = 0.f, navL = 0.f;
    if (c > 0.f){ posL = p / c; navL = n / c; }
    out[0] = posL + navL + 0.1f * (accf[0] / (float)(NROW * KDIM));
  }
}

extern "C" void kernel_launch(void* const* d_in, const int* in_sizes, int n_in,
                              void* d_out, int out_size, void* d_ws, size_t ws_size,
                              hipStream_t stream){
  const float* u = (const float*)d_in[0];
  const int* y = (const int*)d_in[1];
  char* ws = (char*)d_ws;
  float* accf = (float*)ws;                        // [0]=qSum
  int* cnt = (int*)(ws + 64);                      // 256 ints
  float* rowRes = (float*)(ws + 4096);             // 6144 * 16 B = 98304 B
  unsigned char* lab = (unsigned char*)(ws + 102400);      // 6144 B
  int* simIdx = (int*)(ws + 108544);               // 200*512 ints = 409600 B
  _Float16* uhswz = (_Float16*)(ws + 518144);      // 1572864 B
  const size_t ibufOff = 518144 + (size_t)NROW * KDIM * 2; // 2091008, 16B aligned
  _Float16* ibuf = (_Float16*)(ws + ibufOff);

  hipMemsetAsync(d_ws, 0, 102400, stream);         // accf + cnt + rowRes
  k_labtanh<<<NROW / 4 + (NROW * 16) / 256, 256, 0, stream>>>(y, lab, cnt, simIdx,
                                                              u, uhswz, accf);

  size_t avail = (ws_size > ibufOff) ? ws_size - ibufOff : 0;
  long maxRows = (long)(avail / ((size_t)NROW * 2));
  maxRows = (maxRows / 128) * 128;
  if (maxRows > NROW) maxRows = NROW;
  if (maxRows < 128) maxRows = 128;

  for (int r0 = 0; r0 < NROW; r0 += (int)maxRows){
    int rows = NROW - r0;
    if (rows > maxRows) rows = (int)maxRows;
    if (rows == NROW){
      k_mm<<<dim3(48 * 49 / 2), 512, 0, stream>>>(uhswz, ibuf, r0, 1);   // triangular
    } else {
      k_mm<<<dim3(48, rows / 128), 512, 0, stream>>>(uhswz, ibuf, r0, 0);
    }
    k_stats<<<rows / 4, 256, 0, stream>>>(ibuf, lab, cnt, simIdx, rowRes, r0);
  }
  k_final<<<1, 256, 0, stream>>>(accf, rowRes, (float*)d_out);
}